// Round 1
// baseline (301.529 us; speedup 1.0000x reference)
//
#include <hip/hip_runtime.h>
#include <hip/hip_bf16.h>

#define B_N   131072
#define E_N   8
#define D_N   128
#define H_N   128
#define K_N   1024
#define MBLK  16
#define NTHR  256

typedef __attribute__((ext_vector_type(8))) short bf16x8;
typedef __attribute__((ext_vector_type(4))) float f32x4;
typedef __attribute__((ext_vector_type(4))) unsigned short u16x4;

__device__ __forceinline__ unsigned short f2bf(float f) {
    union { float f; unsigned int i; } c; c.f = f;
    unsigned int x = c.i;
    // round-to-nearest-even bf16 (inputs are finite normals)
    return (unsigned short)((x + 0x7fffu + ((x >> 16) & 1u)) >> 16);
}
__device__ __forceinline__ float bf2f(unsigned short u) {
    union { unsigned int i; float f; } c; c.i = ((unsigned int)u) << 16; return c.f;
}

// ---------------------------------------------------------------------------
// Prep: repack gate_w1 [1024][128] f32 -> bf16 MFMA B-fragment order in d_ws.
// Frag (kstep, nt): lane l holds B[kstep*32 + (l>>4)*8 + j][nt*16 + (l&15)],
// j = 0..7, stored as 16 contiguous bytes at frag[( (kstep*8+nt)*64 + l )*8].
// ---------------------------------------------------------------------------
__global__ void prep_w1_frags(const float* __restrict__ w1,
                              unsigned short* __restrict__ frag) {
    int t    = blockIdx.x * blockDim.x + threadIdx.x;   // 0..16383
    int lane = t & 63;
    int fgi  = t >> 6;                                  // kstep*8 + nt
    int kst  = fgi >> 3;
    int nt   = fgi & 7;
    int n    = nt * 16 + (lane & 15);
    int k0   = kst * 32 + (lane >> 4) * 8;
    bf16x8 v;
    #pragma unroll
    for (int j = 0; j < 8; ++j)
        v[j] = (short)f2bf(w1[(k0 + j) * H_N + n]);
    *reinterpret_cast<bf16x8*>(frag + (size_t)t * 8) = v;
}

// ---------------------------------------------------------------------------
// Fused MoE kernel: one block = 16 samples.
// ---------------------------------------------------------------------------
__global__ __launch_bounds__(NTHR, 3)
void moe_fused(const float* __restrict__ feats,
               const unsigned short* __restrict__ w1frag,
               const float* __restrict__ gate_b1,
               const float* __restrict__ ln1_g,
               const float* __restrict__ ln1_b,
               const float* __restrict__ gate_w2,
               const float* __restrict__ gate_b2,
               const float* __restrict__ out_g,
               const float* __restrict__ out_b,
               float* __restrict__ out)
{
    // swizzled bf16 features: element (m,k) at m*1024 + ((k>>3)^(m&7))*8 + (k&7)
    __shared__ __attribute__((aligned(16))) unsigned short featS[MBLK * K_N]; // 32 KB
    __shared__ float hS[MBLK * 132];                                          // padded rows
    __shared__ float w2tS[E_N * H_N];                                         // W2^T [e][j]
    __shared__ float gb1S[H_N], l1gS[H_N], l1bS[H_N], ogS[D_N], obS[D_N];
    __shared__ float gb2S[E_N];
    __shared__ float scoreS[MBLK * E_N];

    const int tid = threadIdx.x;
    const int b0  = blockIdx.x * MBLK;

    // ---- phase 0: tiny params -> LDS
    if (tid < 128) {
        gb1S[tid] = gate_b1[tid];
        l1gS[tid] = ln1_g[tid];
        l1bS[tid] = ln1_b[tid];
        ogS[tid]  = out_g[tid];
        obS[tid]  = out_b[tid];
    }
    if (tid < 8) gb2S[tid] = gate_b2[tid];
    for (int idx = tid; idx < H_N * E_N; idx += NTHR)
        w2tS[(idx & 7) * H_N + (idx >> 3)] = gate_w2[idx];   // [j][e] -> [e][j]

    // ---- phase 1: stream features -> bf16 LDS (swizzled)
    #pragma unroll
    for (int e = 0; e < E_N; ++e) {
        const f32x4* src = reinterpret_cast<const f32x4*>(
            feats + ((size_t)e * B_N + b0) * D_N);
        #pragma unroll
        for (int i = 0; i < (MBLK * D_N / 4) / NTHR; ++i) {  // = 2
            int f   = tid + i * NTHR;        // f32x4 index in 16x128 chunk
            f32x4 v = src[f];
            int m   = f >> 5;                // 32 f32x4 per sample-row
            int dq  = f & 31;
            int k   = e * D_N + dq * 4;
            int uoff = m * K_N + ((((k >> 3) ^ (m & 7)) << 3) | (k & 7));
            u16x4 u;
            u[0] = f2bf(v[0]); u[1] = f2bf(v[1]);
            u[2] = f2bf(v[2]); u[3] = f2bf(v[3]);
            *reinterpret_cast<u16x4*>(&featS[uoff]) = u;
        }
    }
    __syncthreads();

    // ---- phase 2: GEMM1  h[16][128] = featbf16 @ W1bf16  (MFMA 16x16x32)
    const int wv   = tid >> 6;
    const int lane = tid & 63;
    const int lrow = lane & 15;      // A row / D col-index within tile
    const int lkh  = lane >> 4;      // k-half selector
    const int nt0  = wv * 2, nt1 = nt0 + 1;
    f32x4 acc0 = {0.f, 0.f, 0.f, 0.f};
    f32x4 acc1 = {0.f, 0.f, 0.f, 0.f};
    const bf16x8* wf = reinterpret_cast<const bf16x8*>(w1frag);
    const int arow = lrow * K_N;
    const int asw  = lrow & 7;
    #pragma unroll 4
    for (int kk = 0; kk < 32; ++kk) {
        bf16x8 a  = *reinterpret_cast<const bf16x8*>(
            &featS[arow + ((((kk << 2) + lkh) ^ asw) << 3)]);
        bf16x8 b0 = wf[((kk * 8 + nt0) << 6) + lane];
        bf16x8 b1 = wf[((kk * 8 + nt1) << 6) + lane];
        acc0 = __builtin_amdgcn_mfma_f32_16x16x32_bf16(a, b0, acc0, 0, 0, 0);
        acc1 = __builtin_amdgcn_mfma_f32_16x16x32_bf16(a, b1, acc1, 0, 0, 0);
    }

    // ---- phase 2.5: +bias, exact GELU -> hS
    {
        const int colA = nt0 * 16 + lrow;
        const int colB = nt1 * 16 + lrow;
        #pragma unroll
        for (int r = 0; r < 4; ++r) {
            int row  = lkh * 4 + r;
            float vA = acc0[r] + gb1S[colA];
            float vB = acc1[r] + gb1S[colB];
            vA = 0.5f * vA * (1.f + erff(vA * 0.70710678118654752f));
            vB = 0.5f * vB * (1.f + erff(vB * 0.70710678118654752f));
            hS[row * 132 + colA] = vA;
            hS[row * 132 + colB] = vB;
        }
    }
    __syncthreads();

    // ---- phase 2.6: LN1 + GEMM2 + softmax -> scoreS   (16-lane groups)
    {
        const int row = tid >> 4;      // sample m
        const int gl  = tid & 15;
        const float* hrow = &hS[row * 132 + gl * 8];
        float hv[8];
        #pragma unroll
        for (int j = 0; j < 8; ++j) hv[j] = hrow[j];
        float s = 0.f, sq = 0.f;
        #pragma unroll
        for (int j = 0; j < 8; ++j) { s += hv[j]; sq += hv[j] * hv[j]; }
        #pragma unroll
        for (int msk = 1; msk < 16; msk <<= 1) {
            s  += __shfl_xor(s, msk);
            sq += __shfl_xor(sq, msk);
        }
        float mu  = s * (1.f / 128.f);
        float var = sq * (1.f / 128.f) - mu * mu;
        float rs  = rsqrtf(var + 1e-5f);
        float p[8] = {0.f, 0.f, 0.f, 0.f, 0.f, 0.f, 0.f, 0.f};
        #pragma unroll
        for (int j = 0; j < 8; ++j) {
            int col  = gl * 8 + j;
            float hn = (hv[j] - mu) * rs * l1gS[col] + l1bS[col];
            #pragma unroll
            for (int e = 0; e < 8; ++e) p[e] += hn * w2tS[e * H_N + col];
        }
        #pragma unroll
        for (int msk = 1; msk < 16; msk <<= 1) {
            #pragma unroll
            for (int e = 0; e < 8; ++e) p[e] += __shfl_xor(p[e], msk);
        }
        float lg[8], mx = -3.0e38f;
        #pragma unroll
        for (int e = 0; e < 8; ++e) { lg[e] = p[e] + gb2S[e]; mx = fmaxf(mx, lg[e]); }
        float den = 0.f, ex[8];
        #pragma unroll
        for (int e = 0; e < 8; ++e) { ex[e] = __expf(lg[e] - mx); den += ex[e]; }
        float inv = 1.f / den;
        if (gl < 8) scoreS[row * 8 + gl] = ex[gl] * inv;
    }
    __syncthreads();

    // ---- phase 4: weighted LayerNorm over D, stream out.
    // LN(s*x) = s*(x-mu)*rsqrt(s^2*var + eps)
    {
        const int m  = tid >> 4;       // group = sample
        const int gl = tid & 15;
        #pragma unroll
        for (int e = 0; e < E_N; ++e) {
            int slot = ((e << 4) | gl) ^ (m & 7);
            bf16x8 x8 = *reinterpret_cast<const bf16x8*>(&featS[m * K_N + (slot << 3)]);
            float x[8];
            #pragma unroll
            for (int j = 0; j < 8; ++j) x[j] = bf2f((unsigned short)x8[j]);
            float s = 0.f, sq = 0.f;
            #pragma unroll
            for (int j = 0; j < 8; ++j) { s += x[j]; sq += x[j] * x[j]; }
            #pragma unroll
            for (int msk = 1; msk < 16; msk <<= 1) {
                s  += __shfl_xor(s, msk);
                sq += __shfl_xor(sq, msk);
            }
            float mu  = s * (1.f / 128.f);
            float var = sq * (1.f / 128.f) - mu * mu;
            float sc  = scoreS[m * 8 + e];
            float srs = sc * rsqrtf(sc * sc * var + 1e-5f);
            float* dst = out + ((size_t)e * B_N + b0 + m) * D_N + gl * 8;
            f32x4 o0, o1;
            #pragma unroll
            for (int j = 0; j < 4; ++j)
                o0[j] = (x[j] - mu) * srs * ogS[gl * 8 + j] + obS[gl * 8 + j];
            #pragma unroll
            for (int j = 0; j < 4; ++j)
                o1[j] = (x[4 + j] - mu) * srs * ogS[gl * 8 + 4 + j] + obS[gl * 8 + 4 + j];
            *reinterpret_cast<f32x4*>(dst)     = o0;
            *reinterpret_cast<f32x4*>(dst + 4) = o1;
        }
    }
}

extern "C" void kernel_launch(void* const* d_in, const int* in_sizes, int n_in,
                              void* d_out, int out_size, void* d_ws, size_t ws_size,
                              hipStream_t stream) {
    const float* feats   = (const float*)d_in[0];
    const float* gate_w1 = (const float*)d_in[1];
    const float* gate_b1 = (const float*)d_in[2];
    const float* ln1_g   = (const float*)d_in[3];
    const float* ln1_b   = (const float*)d_in[4];
    const float* gate_w2 = (const float*)d_in[5];
    const float* gate_b2 = (const float*)d_in[6];
    const float* out_g   = (const float*)d_in[7];
    const float* out_b   = (const float*)d_in[8];
    float* outp = (float*)d_out;
    unsigned short* frag = (unsigned short*)d_ws;   // 256 KB bf16 W1 fragments

    prep_w1_frags<<<64, NTHR, 0, stream>>>(gate_w1, frag);
    moe_fused<<<B_N / MBLK, NTHR, 0, stream>>>(
        feats, frag, gate_b1, ln1_g, ln1_b, gate_w2, gate_b2, out_g, out_b, outp);
}